// Round 1
// 836.195 us; speedup vs baseline: 1.0302x; 1.0302x over previous
//
#include <hip/hip_runtime.h>
#include <hip/hip_bf16.h>

#define N_NODES 20000
#define N_EDGES 320000
#define NGRAPH  64
#define FPD     65

typedef __attribute__((ext_vector_type(8))) __bf16 bf16x8;
typedef __attribute__((ext_vector_type(4))) float floatx4;

__device__ inline float bf2f(ushort u) {
    union { unsigned int i; float f; } c; c.i = ((unsigned int)u) << 16; return c.f;
}
__device__ inline ushort f2bf(float v) {
    __hip_bfloat16 h = __float2bfloat16(v);
    return *(ushort*)&h;
}
// async global->LDS, 16 B per lane; LDS dest must be wave-uniform-base + lane*16
__device__ __forceinline__ void gld_lds16(const ushort* g, ushort* l) {
    __builtin_amdgcn_global_load_lds(
        (const __attribute__((address_space(1))) unsigned int*)g,
        (__attribute__((address_space(3))) unsigned int*)l,
        16, 0, 0);
}

// ---------------- CSR build ----------------
__global__ void init_cnt(int* cnt) {
    int i = blockIdx.x * blockDim.x + threadIdx.x;
    if (i < N_NODES) cnt[i] = 1;   // self-loop
}
__global__ void count_in(const int* __restrict__ dst, int* cnt) {
    int e = blockIdx.x * blockDim.x + threadIdx.x;
    if (e < N_EDGES) atomicAdd(&cnt[dst[e]], 1);
}
__global__ void make_dis(const int* __restrict__ cnt, float* dis) {
    int i = blockIdx.x * blockDim.x + threadIdx.x;
    if (i < N_NODES) dis[i] = rsqrtf((float)cnt[i]);
}
__global__ __launch_bounds__(256) void scan_offsets(const int* __restrict__ cnt,
                                                    int* __restrict__ off, int* __restrict__ cursor) {
    __shared__ int part[256];
    int t = threadIdx.x;
    const int chunk = (N_NODES + 255) / 256;
    int lo = t * chunk, hi = min(lo + chunk, N_NODES);
    int s = 0;
    for (int i = lo; i < hi; ++i) s += cnt[i];
    part[t] = s;
    __syncthreads();
    for (int d = 1; d < 256; d <<= 1) {
        int v = (t >= d) ? part[t - d] : 0;
        __syncthreads();
        part[t] += v;
        __syncthreads();
    }
    int base = part[t] - s;
    for (int i = lo; i < hi; ++i) {
        off[i] = base; cursor[i] = base;
        base += cnt[i];
    }
    if (t == 255) off[N_NODES] = part[255];
}
__global__ void fill_csr(const int* __restrict__ src, const int* __restrict__ dst,
                         const float* __restrict__ dis, int* cursor,
                         int* __restrict__ esrc, float* __restrict__ ew) {
    int e = blockIdx.x * blockDim.x + threadIdx.x;
    if (e >= N_EDGES + N_NODES) return;
    int s, d; float w;
    if (e < N_EDGES) { s = src[e]; d = dst[e]; w = dis[s] * dis[d]; }
    else { s = d = e - N_EDGES; w = dis[s] * dis[s]; }
    int pos = atomicAdd(&cursor[d], 1);
    esrc[pos] = s; ew[pos] = w;
}

// ---------------- utility ----------------
__global__ void conv_f32_bf16(const float* __restrict__ in, ushort* __restrict__ out, long long n) {
    long long i = ((long long)blockIdx.x * blockDim.x + threadIdx.x) * 4;
    if (i >= n) return;
    float4 v = *(const float4*)(in + i);
    ushort4 o;
    o.x = f2bf(v.x); o.y = f2bf(v.y); o.z = f2bf(v.z); o.w = f2bf(v.w);
    *(ushort4*)(out + i) = o;
}
// W[K][Nc] f32 -> Wt[Nc][K] bf16
__global__ void transpose_conv(const float* __restrict__ W, ushort* __restrict__ Wt, int K, int Nc) {
    __shared__ float t[32][33];
    int k0 = blockIdx.x * 32, n0 = blockIdx.y * 32;
    int tx = threadIdx.x, ty = threadIdx.y;
    #pragma unroll
    for (int i = 0; i < 4; ++i)
        t[ty + i * 8][tx] = W[(size_t)(k0 + ty + i * 8) * Nc + n0 + tx];
    __syncthreads();
    #pragma unroll
    for (int i = 0; i < 4; ++i)
        Wt[(size_t)(n0 + ty + i * 8) * K + k0 + tx] = f2bf(t[tx][ty + i * 8]);
}

// LDS XOR swizzle: position (row,col-granule) holds global granule (col ^ f(row)),
// f(r)=(r+(r>>2))&3 -> each quad's 16 lanes spread over all 8 bank-groups.
__device__ __forceinline__ int swz(int r) { return (r + (r >> 2)) & 3; }

// ---------------- bf16 MFMA GEMM (m97 128x128 config): C[M,Nc](bf16) = A[M,K] @ Bt[Nc,K]^T
// 4 waves in 2x2, each wave owns a 64x64 sub-tile (4x4 16x16x32 frags), BK=32.
// 1D grid padded to 8*chunk. XCD-aware remap: xcd = bi&7 (round-robin dispatch),
// tile = xcd*chunk + (bi>>3); tiles m-major/n-minor -> contiguous m-panels per XCD L2.
__global__ __launch_bounds__(256) void gemm_bf16_128(
    const ushort* __restrict__ A, const ushort* __restrict__ Bt,
    ushort* __restrict__ C, int M, int K, int Nc, int nt, int total, int chunk)
{
    __shared__ ushort As[128 * 32];
    __shared__ ushort Bs[128 * 32];
    const int bi = blockIdx.x;
    const int tile = (bi & 7) * chunk + (bi >> 3);
    if (tile >= total) return;
    const int bm = (tile / nt) * 128, bn = (tile % nt) * 128;

    const int tid = threadIdx.x;
    const int wid = tid >> 6, lane = tid & 63;
    const int wr = wid >> 1, wc = wid & 1;
    const int quad = lane >> 4, mr = lane & 15;

    floatx4 acc[4][4];
    #pragma unroll
    for (int i = 0; i < 4; ++i)
        #pragma unroll
        for (int j = 0; j < 4; ++j)
            acc[i][j] = (floatx4){0.f, 0.f, 0.f, 0.f};

    for (int k0 = 0; k0 < K; k0 += 32) {
        #pragma unroll
        for (int i = 0; i < 2; ++i) {
            int c = tid + i * 256;
            int row = c >> 2;
            int q = (c & 3) ^ swz(row);                  // permuted global source
            gld_lds16(A + (size_t)(bm + row) * K + k0 + q * 8, &As[c * 8]);
        }
        #pragma unroll
        for (int i = 0; i < 2; ++i) {
            int c = tid + i * 256;
            int row = c >> 2;
            int q = (c & 3) ^ swz(row);
            gld_lds16(Bt + (size_t)(bn + row) * K + k0 + q * 8, &Bs[c * 8]);
        }
        __syncthreads();

        bf16x8 af[4], bfv[4];
        #pragma unroll
        for (int t = 0; t < 4; ++t) {
            int ra = wr * 64 + t * 16 + mr;
            af[t] = *(const bf16x8*)&As[ra * 32 + (quad ^ swz(ra)) * 8];
            int rb = wc * 64 + t * 16 + mr;
            bfv[t] = *(const bf16x8*)&Bs[rb * 32 + (quad ^ swz(rb)) * 8];
        }

        #pragma unroll
        for (int tm = 0; tm < 4; ++tm)
            #pragma unroll
            for (int tn = 0; tn < 4; ++tn)
                acc[tm][tn] = __builtin_amdgcn_mfma_f32_16x16x32_bf16(af[tm], bfv[tn], acc[tm][tn], 0, 0, 0);
        __syncthreads();
    }

    #pragma unroll
    for (int tm = 0; tm < 4; ++tm) {
        int rowb = bm + wr * 64 + tm * 16 + quad * 4;
        #pragma unroll
        for (int r = 0; r < 4; ++r) {
            int row = rowb + r;
            if (row < M) {
                #pragma unroll
                for (int tn = 0; tn < 4; ++tn)
                    C[(size_t)row * Nc + bn + wc * 64 + tn * 16 + mr] = f2bf(acc[tm][tn][r]);
            }
        }
    }
}

// ---------------- legacy 256x64 GEMM (kept for Nc % 128 != 0, i.e. layer 3) ----------------
__global__ __launch_bounds__(256) void gemm_bf16(
    const ushort* __restrict__ A, const ushort* __restrict__ Bt,
    ushort* __restrict__ C, int M, int K, int Nc, int nt, int total, int chunk)
{
    __shared__ ushort As[256 * 32];
    __shared__ ushort Bs[64 * 32];
    const int bi = blockIdx.x;
    const int tile = (bi & 7) * chunk + (bi >> 3);
    if (tile >= total) return;
    const int bm = (tile / nt) * 256, bn = (tile % nt) * 64;

    const int tid = threadIdx.x;
    const int wid = tid >> 6, lane = tid & 63;
    const int quad = lane >> 4, mr = lane & 15;

    floatx4 acc[4][4];
    #pragma unroll
    for (int i = 0; i < 4; ++i)
        #pragma unroll
        for (int j = 0; j < 4; ++j)
            acc[i][j] = (floatx4){0.f, 0.f, 0.f, 0.f};

    for (int k0 = 0; k0 < K; k0 += 32) {
        #pragma unroll
        for (int i = 0; i < 4; ++i) {
            int c = tid + i * 256;
            int row = c >> 2;
            int q = (c & 3) ^ swz(row);
            gld_lds16(A + (size_t)(bm + row) * K + k0 + q * 8, &As[c * 8]);
        }
        {
            int row = tid >> 2;
            int q = (tid & 3) ^ swz(row);
            gld_lds16(Bt + (size_t)(bn + row) * K + k0 + q * 8, &Bs[tid * 8]);
        }
        __syncthreads();

        bf16x8 af[4], bfv[4];
        #pragma unroll
        for (int t = 0; t < 4; ++t) {
            int ra = wid * 64 + t * 16 + mr;
            af[t] = *(const bf16x8*)&As[ra * 32 + (quad ^ swz(ra)) * 8];
        }
        #pragma unroll
        for (int t = 0; t < 4; ++t) {
            int rb = t * 16 + mr;
            bfv[t] = *(const bf16x8*)&Bs[rb * 32 + (quad ^ swz(rb)) * 8];
        }

        #pragma unroll
        for (int tm = 0; tm < 4; ++tm)
            #pragma unroll
            for (int tn = 0; tn < 4; ++tn)
                acc[tm][tn] = __builtin_amdgcn_mfma_f32_16x16x32_bf16(af[tm], bfv[tn], acc[tm][tn], 0, 0, 0);
        __syncthreads();
    }

    #pragma unroll
    for (int tm = 0; tm < 4; ++tm) {
        int rowb = bm + wid * 64 + tm * 16 + quad * 4;
        #pragma unroll
        for (int r = 0; r < 4; ++r) {
            int row = rowb + r;
            if (row < M) {
                #pragma unroll
                for (int tn = 0; tn < 4; ++tn)
                    C[(size_t)row * Nc + bn + tn * 16 + mr] = f2bf(acc[tm][tn][r]);
            }
        }
    }
}

static inline void launch_gemm(const ushort* A, const ushort* Bt, ushort* C,
                               int M, int K, int Nc, hipStream_t stream) {
    if (Nc % 128 == 0) {
        int mt = (M + 127) / 128, nt = Nc / 128;
        int total = mt * nt;
        int chunk = (total + 7) / 8;
        gemm_bf16_128<<<8 * chunk, 256, 0, stream>>>(A, Bt, C, M, K, Nc, nt, total, chunk);
    } else {
        int mt = (M + 255) / 256, nt = Nc / 64;
        int total = mt * nt;
        int chunk = (total + 7) / 8;
        gemm_bf16<<<8 * chunk, 256, 0, stream>>>(A, Bt, C, M, K, Nc, nt, total, chunk);
    }
}

// ---------------- CSR gather, 4-edge batched, ushort4 loads ----------------
template<int DF, int TPN>
__global__ __launch_bounds__(256) void gather_csr4(
    const ushort* __restrict__ h, const int* __restrict__ off,
    const int* __restrict__ esrc, const float* __restrict__ ew,
    const float* __restrict__ bias, ushort* __restrict__ out_bf,
    float* __restrict__ out_f32, int wbf, int wf32)
{
    constexpr int NPB = 256 / TPN;
    constexpr int H4  = DF / 4;
    constexpr int NC  = (H4 + TPN - 1) / TPN;
    int tid = threadIdx.x;
    int n = blockIdx.x * NPB + tid / TPN;
    int t = tid % TPN;
    if (n >= N_NODES) return;

    float4 acc[NC];
    #pragma unroll
    for (int c = 0; c < NC; ++c) acc[c] = make_float4(0.f, 0.f, 0.f, 0.f);

    int e0 = off[n], e1 = off[n + 1];
    for (int e = e0; e < e1; e += 4) {
        int s0 = esrc[e];  float w0 = ew[e];
        int s1 = s0, s2 = s0, s3 = s0;
        float w1 = 0.f, w2 = 0.f, w3 = 0.f;
        if (e + 1 < e1) { s1 = esrc[e + 1]; w1 = ew[e + 1]; }
        if (e + 2 < e1) { s2 = esrc[e + 2]; w2 = ew[e + 2]; }
        if (e + 3 < e1) { s3 = esrc[e + 3]; w3 = ew[e + 3]; }
        const ushort* r0 = h + (size_t)s0 * DF;
        const ushort* r1 = h + (size_t)s1 * DF;
        const ushort* r2 = h + (size_t)s2 * DF;
        const ushort* r3 = h + (size_t)s3 * DF;
        #pragma unroll
        for (int c = 0; c < NC; ++c) {
            int f4 = t + c * TPN;
            if (H4 % TPN == 0 || f4 < H4) {
                ushort4 v0 = *(const ushort4*)(r0 + f4 * 4);
                ushort4 v1 = *(const ushort4*)(r1 + f4 * 4);
                ushort4 v2 = *(const ushort4*)(r2 + f4 * 4);
                ushort4 v3 = *(const ushort4*)(r3 + f4 * 4);
                acc[c].x += w0 * bf2f(v0.x) + w1 * bf2f(v1.x) + w2 * bf2f(v2.x) + w3 * bf2f(v3.x);
                acc[c].y += w0 * bf2f(v0.y) + w1 * bf2f(v1.y) + w2 * bf2f(v2.y) + w3 * bf2f(v3.y);
                acc[c].z += w0 * bf2f(v0.z) + w1 * bf2f(v1.z) + w2 * bf2f(v2.z) + w3 * bf2f(v3.z);
                acc[c].w += w0 * bf2f(v0.w) + w1 * bf2f(v1.w) + w2 * bf2f(v2.w) + w3 * bf2f(v3.w);
            }
        }
    }

    #pragma unroll
    for (int c = 0; c < NC; ++c) {
        int f4 = t + c * TPN;
        if (H4 % TPN == 0 || f4 < H4) {
            float4 bv = *(const float4*)(bias + f4 * 4);
            float vx = fmaxf(acc[c].x + bv.x, 0.f);
            float vy = fmaxf(acc[c].y + bv.y, 0.f);
            float vz = fmaxf(acc[c].z + bv.z, 0.f);
            float vw = fmaxf(acc[c].w + bv.w, 0.f);
            if (wbf) {
                ushort4 o;
                o.x = f2bf(vx); o.y = f2bf(vy); o.z = f2bf(vz); o.w = f2bf(vw);
                *(ushort4*)(out_bf + (size_t)n * DF + f4 * 4) = o;
            }
            if (wf32)
                *(float4*)(out_f32 + (size_t)n * DF + f4 * 4) = make_float4(vx, vy, vz, vw);
        }
    }
}

// ---------------- mean pool over graphs (batch sorted -> contiguous ranges) ----------------
__global__ void graph_bounds(const int* __restrict__ batch, int* __restrict__ gstart) {
    int n = blockIdx.x * blockDim.x + threadIdx.x;
    if (n >= N_NODES) return;
    int b = batch[n];
    int bp = (n == 0) ? -1 : batch[n - 1];
    for (int g = bp + 1; g <= b; ++g) gstart[g] = n;
    if (n == N_NODES - 1)
        for (int g = b + 1; g <= NGRAPH; ++g) gstart[g] = N_NODES;
}
__global__ __launch_bounds__(320) void pool_graph(
    const float* __restrict__ x, const int* __restrict__ gstart, float* __restrict__ pool)
{
    int g = blockIdx.x;
    int t = threadIdx.x;
    int s = gstart[g], e = gstart[g + 1];
    float a0 = 0.f, a1 = 0.f, a2 = 0.f, a3 = 0.f;
    int n = s;
    for (; n + 3 < e; n += 4) {
        a0 += x[(size_t)(n + 0) * 320 + t];
        a1 += x[(size_t)(n + 1) * 320 + t];
        a2 += x[(size_t)(n + 2) * 320 + t];
        a3 += x[(size_t)(n + 3) * 320 + t];
    }
    for (; n < e; ++n) a0 += x[(size_t)n * 320 + t];
    float acc = (a0 + a1) + (a2 + a3);
    pool[g * 320 + t] = acc / fmaxf((float)(e - s), 1.0f);
}

// ---------------- MLP head: split-K GEMM ----------------
template<int K, int SPLIT, int RELU>
__global__ __launch_bounds__(256) void head_gemm_sk(
    const float* __restrict__ in, int istride,
    const float* __restrict__ W, const float* __restrict__ b,
    float* __restrict__ out, int M, int Nc)
{
    constexpr int KQ = K / SPLIT;
    int idx = blockIdx.x * blockDim.x + threadIdx.x;
    int oi = idx / SPLIT, r = idx % SPLIT;
    if (oi >= M * Nc) return;
    int m = oi / Nc, c = oi % Nc;
    const float* ip = in + (size_t)m * istride + r * KQ;
    const float* wp = W + (size_t)r * KQ * Nc + c;
    float a0 = 0.f, a1 = 0.f, a2 = 0.f, a3 = 0.f;
    #pragma unroll
    for (int k = 0; k < KQ; k += 4) {
        float4 v = *(const float4*)(ip + k);
        a0 += v.x * wp[(size_t)(k + 0) * Nc];
        a1 += v.y * wp[(size_t)(k + 1) * Nc];
        a2 += v.z * wp[(size_t)(k + 2) * Nc];
        a3 += v.w * wp[(size_t)(k + 3) * Nc];
    }
    float s = (a0 + a1) + (a2 + a3);
    #pragma unroll
    for (int o = 1; o < SPLIT; o <<= 1) s += __shfl_xor(s, o, 64);
    if (r == 0) {
        s += b[c];
        out[oi] = RELU ? fmaxf(s, 0.f) : s;
    }
}

__global__ void concat_pad(const float* __restrict__ fp, const float* __restrict__ xt,
                           float* __restrict__ xc) {
    int idx = blockIdx.x * blockDim.x + threadIdx.x;
    if (idx >= NGRAPH * 208) return;
    int g = idx / 208, j = idx % 208;
    float v = 0.f;
    if (j < FPD) v = fp[g * FPD + j];
    else if (j < 193) v = xt[g * 128 + (j - FPD)];
    xc[idx] = v;
}
__global__ void pad_w(const float* __restrict__ Wf1, float* __restrict__ Wp) {
    int idx = blockIdx.x * blockDim.x + threadIdx.x;
    if (idx >= 208 * 1024) return;
    int k = idx / 1024;
    Wp[idx] = (k < 193) ? Wf1[idx] : 0.f;
}

__global__ __launch_bounds__(256) void head_out(
    const float* __restrict__ f2, const float* __restrict__ Wo,
    const float* __restrict__ bo, float* __restrict__ out)
{
    int m = blockIdx.x;
    int t = threadIdx.x;
    float2 v = *(const float2*)(f2 + (size_t)m * 512 + t * 2);
    float2 w = *(const float2*)(Wo + t * 2);
    float s = v.x * w.x + v.y * w.y;
    #pragma unroll
    for (int o = 32; o > 0; o >>= 1) s += __shfl_down(s, o, 64);
    __shared__ float ps[4];
    if ((t & 63) == 0) ps[t >> 6] = s;
    __syncthreads();
    if (t == 0) out[m] = ps[0] + ps[1] + ps[2] + ps[3] + bo[0];
}

extern "C" void kernel_launch(void* const* d_in, const int* in_sizes, int n_in,
                              void* d_out, int out_size, void* d_ws, size_t ws_size,
                              hipStream_t stream) {
    const float* x    = (const float*)d_in[0];
    const int*   eidx = (const int*)d_in[1];
    const int*   batch= (const int*)d_in[2];
    const float* fp_x = (const float*)d_in[3];
    const float* W1 = (const float*)d_in[4];  const float* b1 = (const float*)d_in[5];
    const float* W2 = (const float*)d_in[6];  const float* b2 = (const float*)d_in[7];
    const float* W3 = (const float*)d_in[8];  const float* b3 = (const float*)d_in[9];
    const float* Wg1= (const float*)d_in[10]; const float* bg1= (const float*)d_in[11];
    const float* Wg2= (const float*)d_in[12]; const float* bg2= (const float*)d_in[13];
    const float* Wf1= (const float*)d_in[14]; const float* bf1= (const float*)d_in[15];
    const float* Wf2= (const float*)d_in[16]; const float* bf2= (const float*)d_in[17];
    const float* Wo = (const float*)d_in[18]; const float* bo = (const float*)d_in[19];
    float* out = (float*)d_out;

    const int* src = eidx;
    const int* dst = eidx + N_EDGES;

    // ---- workspace layout ----
    char* p = (char*)d_ws;
    float* dis   = (float*)p;  p += 20480 * 4;
    int*   cntI  = (int*)p;    p += 20480 * 4;
    int*   off   = (int*)p;    p += 20480 * 4;
    int*   cursor= (int*)p;    p += 20480 * 4;
    int*   gstart= (int*)p;    p += 128 * 4;
    int*   esrc  = (int*)p;    p += 340992 * 4;
    float* ew    = (float*)p;  p += 340992 * 4;
    ushort* xbf  = (ushort*)p; p += (size_t)N_NODES * 1280 * 2;
    ushort* hbf  = (ushort*)p; p += (size_t)N_NODES * 1280 * 2;
    ushort* abf  = (ushort*)p; p += (size_t)N_NODES * 1280 * 2;
    float* a3f   = (float*)p;  p += (size_t)N_NODES * 320 * 4;
    ushort* Wt   = (ushort*)p; p += (size_t)1280 * 1280 * 2;
    float* pool  = (float*)p;  p += NGRAPH * 320 * 4;
    float* m1    = (float*)p;  p += NGRAPH * 1024 * 4;
    float* m2    = (float*)p;  p += NGRAPH * 128 * 4;
    float* xc    = (float*)p;  p += NGRAPH * 208 * 4;
    float* f1    = (float*)p;  p += NGRAPH * 1024 * 4;
    float* f2    = (float*)p;  p += NGRAPH * 512 * 4;
    float* Wf1p  = (float*)p;  p += 208 * 1024 * 4;

    // ---- CSR build ----
    init_cnt<<<(N_NODES + 255) / 256, 256, 0, stream>>>(cntI);
    count_in<<<(N_EDGES + 255) / 256, 256, 0, stream>>>(dst, cntI);
    make_dis<<<(N_NODES + 255) / 256, 256, 0, stream>>>(cntI, dis);
    scan_offsets<<<1, 256, 0, stream>>>(cntI, off, cursor);
    fill_csr<<<(N_EDGES + N_NODES + 255) / 256, 256, 0, stream>>>(src, dst, dis, cursor, esrc, ew);
    graph_bounds<<<(N_NODES + 255) / 256, 256, 0, stream>>>(batch, gstart);

    // ---- layer 1 ----
    {
        long long ne = (long long)N_NODES * 1280;
        conv_f32_bf16<<<(unsigned)((ne / 4 + 255) / 256), 256, 0, stream>>>(x, xbf, ne);
        transpose_conv<<<dim3(1280 / 32, 1280 / 32), dim3(32, 8), 0, stream>>>(W1, Wt, 1280, 1280);
        launch_gemm(xbf, Wt, hbf, N_NODES, 1280, 1280, stream);
        gather_csr4<1280, 256><<<N_NODES, 256, 0, stream>>>(hbf, off, esrc, ew, b1, abf, (float*)nullptr, 1, 0);
    }
    // ---- layer 2 ----
    {
        transpose_conv<<<dim3(1280 / 32, 640 / 32), dim3(32, 8), 0, stream>>>(W2, Wt, 1280, 640);
        launch_gemm(abf, Wt, hbf, N_NODES, 1280, 640, stream);
        gather_csr4<640, 256><<<N_NODES, 256, 0, stream>>>(hbf, off, esrc, ew, b2, abf, (float*)nullptr, 1, 0);
    }
    // ---- layer 3 ----
    {
        transpose_conv<<<dim3(640 / 32, 320 / 32), dim3(32, 8), 0, stream>>>(W3, Wt, 640, 320);
        launch_gemm(abf, Wt, hbf, N_NODES, 640, 320, stream);
        gather_csr4<320, 128><<<(N_NODES + 1) / 2, 256, 0, stream>>>(hbf, off, esrc, ew, b3, (ushort*)nullptr, a3f, 0, 1);
    }

    // ---- global mean pool ----
    pool_graph<<<NGRAPH, 320, 0, stream>>>(a3f, gstart, pool);

    // ---- MLP head (split-K) ----
    head_gemm_sk<320, 4, 1><<<(NGRAPH * 1024 * 4 + 255) / 256, 256, 0, stream>>>(pool, 320, Wg1, bg1, m1, NGRAPH, 1024);
    head_gemm_sk<1024, 8, 0><<<(NGRAPH * 128 * 8 + 255) / 256, 256, 0, stream>>>(m1, 1024, Wg2, bg2, m2, NGRAPH, 128);
    concat_pad<<<(NGRAPH * 208 + 255) / 256, 256, 0, stream>>>(fp_x, m2, xc);
    pad_w<<<(208 * 1024 + 255) / 256, 256, 0, stream>>>(Wf1, Wf1p);
    head_gemm_sk<208, 4, 1><<<(NGRAPH * 1024 * 4 + 255) / 256, 256, 0, stream>>>(xc, 208, Wf1p, bf1, f1, NGRAPH, 1024);
    head_gemm_sk<1024, 8, 1><<<(NGRAPH * 512 * 8 + 255) / 256, 256, 0, stream>>>(f1, 1024, Wf2, bf2, f2, NGRAPH, 512);
    head_out<<<NGRAPH, 256, 0, stream>>>(f2, Wo, bo, out);
}